// Round 8
// baseline (122.157 us; speedup 1.0000x reference)
//
#include <hip/hip_runtime.h>
#include <stdint.h>

#define LOG2E 1.4426950408889634f

typedef __attribute__((ext_vector_type(8))) __bf16 bf16x8;
typedef __attribute__((ext_vector_type(4))) __bf16 bf16x4;
typedef __attribute__((ext_vector_type(4))) float f32x4;

__device__ inline void gll16(const void* g, void* l) {
  __builtin_amdgcn_global_load_lds(
      (const __attribute__((address_space(1))) void*)g,
      (__attribute__((address_space(3))) void*)l, 16, 0, 0);
}

// ---------------- fp32 -> bf16 conversion (all 5 tensors, one launch) ----------------
__global__ __launch_bounds__(256) void cvt_all(
    const float* __restrict__ hs, const float* __restrict__ wq,
    const float* __restrict__ wk, const float* __restrict__ wv,
    const float* __restrict__ wo,
    __bf16* __restrict__ hsb, __bf16* __restrict__ wqb, __bf16* __restrict__ wkb,
    __bf16* __restrict__ wvb, __bf16* __restrict__ wob) {
  int bid = blockIdx.x;
  const float* s; __bf16* d; int i;
  if (bid < 4096) { s = hs; d = hsb; i = bid * 256 + threadIdx.x; }
  else {
    int seg = (bid - 4096) >> 10;
    i = ((bid - 4096) & 1023) * 256 + threadIdx.x;
    s = seg == 0 ? wq : seg == 1 ? wk : seg == 2 ? wv : wo;
    d = seg == 0 ? wqb : seg == 1 ? wkb : seg == 2 ? wvb : wob;
  }
  float4 v = ((const float4*)s)[i];
  bf16x4 o;
  o[0] = (__bf16)v.x; o[1] = (__bf16)v.y; o[2] = (__bf16)v.z; o[3] = (__bf16)v.w;
  *(bf16x4*)&d[(size_t)i * 4] = o;
}

// ---------------- merged QKV projection GEMM ----------------
#define KSCALE 0.18033688011112042f  // HD^-0.5 * log2(e)
__global__ __launch_bounds__(256, 3) void qkv_gemm(
    const __bf16* __restrict__ hsb, const __bf16* __restrict__ wqb,
    const __bf16* __restrict__ wkb, const __bf16* __restrict__ wvb,
    __bf16* __restrict__ qbuf, __bf16* __restrict__ kbuf,
    __bf16* __restrict__ vtb) {
  constexpr int K = 1024;
  __shared__ __align__(16) __bf16 lta[128 * 32];
  __shared__ __align__(16) __bf16 ltb[128 * 32];
  const int bid = blockIdx.x;
  const int z = bid >> 8, r = bid & 255;
  const __bf16 *A, *Bt;
  int m0, n0;
  if (z < 2) {
    A = hsb; Bt = z ? wkb : wqb;
    m0 = (r & 31) * 128; n0 = (r >> 5) * 128;
  } else {
    A = wvb; Bt = hsb;
    m0 = (r & 7) * 128; n0 = (r >> 3) * 128;
  }
  const int tid = threadIdx.x;
  const int w = tid >> 6, l = tid & 63;
  const int lg = l >> 4, lr = l & 15;
  const int wm = (w >> 1) * 64, wn = (w & 1) * 64;
  f32x4 acc[4][4] = {};
  const int srow = w * 16 + (l >> 2);
  const int scol = (l & 3) * 8;
  const __bf16* ga = A + (size_t)(m0 + srow) * K + scol;
  const __bf16* gb = Bt + (size_t)(n0 + srow) * K + scol;
  __bf16* la = &lta[(size_t)w * 16 * 32];
  __bf16* lb = &ltb[(size_t)w * 16 * 32];
  for (int k0 = 0; k0 < K; k0 += 32) {
    __syncthreads();
    gll16(ga + k0, la);
    gll16(ga + 64 * K + k0, la + 64 * 32);
    gll16(gb + k0, lb);
    gll16(gb + 64 * K + k0, lb + 64 * 32);
    __syncthreads();
    bf16x8 af[4], bfr[4];
#pragma unroll
    for (int i = 0; i < 4; ++i) {
      af[i]  = *(const bf16x8*)&lta[(wm + i * 16 + lr) * 32 + lg * 8];
      bfr[i] = *(const bf16x8*)&ltb[(wn + i * 16 + lr) * 32 + lg * 8];
    }
#pragma unroll
    for (int i = 0; i < 4; ++i)
#pragma unroll
      for (int j = 0; j < 4; ++j)
        acc[i][j] = __builtin_amdgcn_mfma_f32_16x16x32_bf16(af[i], bfr[j], acc[i][j], 0, 0, 0);
  }
#pragma unroll
  for (int i = 0; i < 4; ++i)
#pragma unroll
    for (int j = 0; j < 4; ++j)
#pragma unroll
      for (int rr = 0; rr < 4; ++rr) {
        int gm = m0 + wm + i * 16 + lg * 4 + rr;
        int gn = n0 + wn + j * 16 + lr;
        float v = acc[i][j][rr];
        if (z < 2) {
          int bb = gm >> 11, s = gm & 2047, hh = gn >> 6, d = gn & 63;
          __bf16* dst = z ? kbuf : qbuf;
          if (z) v *= KSCALE;
          dst[(((size_t)bb * 16 + hh) * 2048 + s) * 64 + d] = (__bf16)v;
        } else {
          int bb = gn >> 11, s = gn & 2047, hh = gm >> 6, d = gm & 63;
          vtb[(((size_t)bb * 16 + hh) * 64 + d) * 2048 + s] = (__bf16)v;
        }
      }
}

// ---------------- output GEMM: 128x64 tiles -> 512 blocks (2/CU) ----------------
__global__ __launch_bounds__(256, 2) void gemm_out(const __bf16* __restrict__ A,
                                                   const __bf16* __restrict__ Bt,
                                                   float* __restrict__ C,
                                                   int M, int N) {
  constexpr int K = 1024;
  __shared__ __align__(16) __bf16 lta[128 * 32];
  __shared__ __align__(16) __bf16 ltb[64 * 32];
  const int tid = threadIdx.x;
  const int w = tid >> 6, l = tid & 63;
  const int lg = l >> 4, lr = l & 15;
  const int m0 = blockIdx.x * 128, n0 = blockIdx.y * 64;
  const int wm = (w >> 1) * 64, wn = (w & 1) * 32;
  f32x4 acc[4][2] = {};
  const int srow = tid >> 2;          // 0..63
  const int scol = (tid & 3) * 8;
  const __bf16* ga = A + (size_t)(m0 + srow) * K + scol;
  const __bf16* gb = Bt + (size_t)(n0 + srow) * K + scol;
  __bf16* la = &lta[(size_t)w * 512];
  __bf16* lb = &ltb[(size_t)w * 512];
  for (int k0 = 0; k0 < K; k0 += 32) {
    __syncthreads();
    gll16(ga + k0, la);
    gll16(ga + (size_t)64 * K + k0, la + 64 * 32);
    gll16(gb + k0, lb);
    __syncthreads();
    bf16x8 af[4], bfr[2];
#pragma unroll
    for (int i = 0; i < 4; ++i)
      af[i]  = *(const bf16x8*)&lta[(wm + i * 16 + lr) * 32 + lg * 8];
#pragma unroll
    for (int j = 0; j < 2; ++j)
      bfr[j] = *(const bf16x8*)&ltb[(wn + j * 16 + lr) * 32 + lg * 8];
#pragma unroll
    for (int i = 0; i < 4; ++i)
#pragma unroll
      for (int j = 0; j < 2; ++j)
        acc[i][j] = __builtin_amdgcn_mfma_f32_16x16x32_bf16(af[i], bfr[j], acc[i][j], 0, 0, 0);
  }
#pragma unroll
  for (int i = 0; i < 4; ++i)
#pragma unroll
    for (int j = 0; j < 2; ++j)
#pragma unroll
      for (int rr = 0; rr < 4; ++rr) {
        int gm = m0 + wm + i * 16 + lg * 4 + rr;
        int gn = n0 + wn + j * 16 + lr;
        C[(size_t)gm * N + gn] = acc[i][j][rr];
      }
}

// ---------------- attention + memory retrieval ----------------
// 512 blocks (p = bx>>5 in 0..15, bh = bx&31), 4 waves. Each block processes
// 64-row q-tiles i = p then i = 31-p (equal ~17 KV64-iters for every block).
// Wave roles: qh = w&1 (q rows i*64+qh*32..+31, mf=2), par = w>>1 (KV-split:
// pair0 = tiles [0,cA), pair1 = [cA,ntk)). LDS 40960 B -> 4 blocks/CU =
// 16 waves/CU. Swapped QK^T, per-lane q=lr softmax in exp2 domain (K
// pre-scaled). XOR-swizzled 64-col LDS; K/V staged via global_load_lds with
// pre-swizzled global source (col8 = (l&7)^(l>>3), constant per thread).
#define DEFER_THR 11.5f
#define SWZ64(row, col) (((row) << 6) + ((col) ^ (((row) & 7) << 3)))

__global__ __launch_bounds__(256, 4) void attn_kernel(
    const __bf16* __restrict__ qb,    // [32][2048][64]
    const __bf16* __restrict__ kb,    // [32][2048][64] (pre-scaled)
    const __bf16* __restrict__ vtb,   // [32][64][2048]
    const float* __restrict__ memory, // [16][64][64]
    const float* __restrict__ memnorm,// [16][64]
    const float* __restrict__ beta,   // [16]
    __bf16* __restrict__ comb)        // [4096][1024]
{
  __shared__ __align__(16) __bf16 kt[2][64 * 64];  // 16 KB (merge: dumpO)
  __shared__ __align__(16) __bf16 vt[2][64 * 64];  // 16 KB (merge: mt + ML)
  __shared__ __align__(16) __bf16 pt[4][16 * 64];  // 8 KB   -> 40960 B total

  const int tid = threadIdx.x;
  const int w = tid >> 6, l = tid & 63;
  const int lg = l >> 4, lr = l & 15;
  const int qh = w & 1, par = w >> 1;
  const int p = blockIdx.x >> 5;
  const int bh = blockIdx.x & 31;
  const int hh = bh & 15, b = bh >> 4;

  const float gate = 1.f / (1.f + __builtin_amdgcn_exp2f(-beta[hh] * LOG2E));
  const float og = 1.f - gate;

  // staging addressing (constant per thread): chunk c = i*128 + qh*64 + l
  // row/d = i*16 + qh*8 + (l>>3); col8 = (l&7) ^ (l>>3)  [since row&7 = l>>3]
  const int srw = qh * 8 + (l >> 3);
  const int c8 = ((l & 7) ^ (l >> 3)) * 8;
  const __bf16* kbase = kb + ((size_t)bh * 2048 + srw) * 64 + c8;     // + kvg*4096 + i*1024
  const __bf16* vbase = vtb + ((size_t)bh * 64 + srw) * 2048 + c8;    // + kvg*64 + i*32768

  for (int phase = 0; phase < 2; ++phase) {
    const int ti = phase ? (31 - p) : p;
    const int wq0 = ti * 64 + qh * 32;
    const int ntk = ti + 1;                 // KV64 tiles in causal range
    const int cA = (ntk + 1) >> 1;
    const int cnt = par ? (ntk - cA) : cA;
    const int kvg0 = par ? cA : 0;          // first KV64 tile index for this pair

    // ---- Q fragments (per-lane: row/col = lr; mf picks 16-row sub-block) ----
    bf16x8 qf[2][2];
#pragma unroll
    for (int mf = 0; mf < 2; ++mf)
#pragma unroll
      for (int kk = 0; kk < 2; ++kk)
        qf[mf][kk] = *(const bf16x8*)(qb + ((size_t)bh * 2048 + wq0 + mf * 16 + lr) * 64 + kk * 32 + lg * 8);

    float mrun[2] = {-1e30f, -1e30f}, lsum[2] = {0.f, 0.f};
    f32x4 apv[2][4] = {};

    for (int kv = 0; kv < cA; ++kv) {
      const bool vcur = kv < cnt;
      const int kvg = kvg0 + kv;
      __syncthreads();
      if (vcur) {
#pragma unroll
        for (int i = 0; i < 4; ++i) {
          gll16(kbase + (size_t)kvg * 4096 + i * 1024, &kt[par][i * 1024 + qh * 512]);
          gll16(vbase + (size_t)i * 32768 + kvg * 64, &vt[par][i * 1024 + qh * 512]);
        }
      }
      __syncthreads();
      if (!vcur) continue;
      const int kv0 = kvg * 64;

      // ---- QK^T swapped: sc[mf][nf]: k = kv0+nf*16+lg*4+r, q = wq0+mf*16+lr
      f32x4 sc[2][4] = {};
#pragma unroll
      for (int kk = 0; kk < 2; ++kk)
#pragma unroll
        for (int nf = 0; nf < 4; ++nf) {
          bf16x8 kf = *(const bf16x8*)&kt[par][SWZ64(nf * 16 + lr, kk * 32 + lg * 8)];
#pragma unroll
          for (int mf = 0; mf < 2; ++mf)
            sc[mf][nf] = __builtin_amdgcn_mfma_f32_16x16x32_bf16(kf, qf[mf][kk], sc[mf][nf], 0, 0, 0);
        }

      // ---- causal mask (diagonal tile only) ----
      if (kv0 + 63 > wq0) {
#pragma unroll
        for (int mf = 0; mf < 2; ++mf) {
          const int qrow = wq0 + mf * 16 + lr;
#pragma unroll
          for (int nf = 0; nf < 4; ++nf)
#pragma unroll
            for (int r = 0; r < 4; ++r)
              if (kv0 + nf * 16 + lg * 4 + r > qrow) sc[mf][nf][r] = -1e30f;
        }
      }

      // ---- per-mf max + defer rescale ----
#pragma unroll
      for (int mf = 0; mf < 2; ++mf) {
        f32x4 m4 = sc[mf][0];
#pragma unroll
        for (int nf = 1; nf < 4; ++nf)
#pragma unroll
          for (int r = 0; r < 4; ++r) m4[r] = fmaxf(m4[r], sc[mf][nf][r]);
        float mx = fmaxf(fmaxf(m4[0], m4[1]), fmaxf(m4[2], m4[3]));
        mx = fmaxf(mx, __shfl_xor(mx, 16, 64));
        mx = fmaxf(mx, __shfl_xor(mx, 32, 64));
        if (!__all(mx - mrun[mf] <= DEFER_THR)) {
          float mold = mrun[mf];
          float mn = fmaxf(mold, mx);
          mrun[mf] = mn;
          float scl = __builtin_amdgcn_exp2f(mold - mn);
          lsum[mf] *= scl;
          float sclq[4];
#pragma unroll
          for (int r = 0; r < 4; ++r) sclq[r] = __shfl(scl, (lg << 2) | r, 16);
#pragma unroll
          for (int nf = 0; nf < 4; ++nf)
#pragma unroll
            for (int r = 0; r < 4; ++r) apv[mf][nf][r] *= sclq[r];
        }
      }

      // ---- P(mf=0) -> pt, cache pa0; then P(mf=1) -> pt ----
      bf16x8 pa0[2];
      {
        f32x4 rs4 = {0.f, 0.f, 0.f, 0.f};
#pragma unroll
        for (int nf = 0; nf < 4; ++nf) {
          bf16x4 pk;
#pragma unroll
          for (int r = 0; r < 4; ++r) {
            float pv = __builtin_amdgcn_exp2f(sc[0][nf][r] - mrun[0]);
            rs4[r] += pv;
            pk[r] = (__bf16)pv;
          }
          *(bf16x4*)&pt[w][SWZ64(lr, nf * 16 + lg * 4)] = pk;
        }
        float rs = (rs4[0] + rs4[1]) + (rs4[2] + rs4[3]);
        rs += __shfl_xor(rs, 16, 64);
        rs += __shfl_xor(rs, 32, 64);
        lsum[0] += rs;
#pragma unroll
        for (int kk = 0; kk < 2; ++kk)
          pa0[kk] = *(const bf16x8*)&pt[w][SWZ64(lr, kk * 32 + lg * 8)];
      }
      {
        f32x4 rs4 = {0.f, 0.f, 0.f, 0.f};
#pragma unroll
        for (int nf = 0; nf < 4; ++nf) {
          bf16x4 pk;
#pragma unroll
          for (int r = 0; r < 4; ++r) {
            float pv = __builtin_amdgcn_exp2f(sc[1][nf][r] - mrun[1]);
            rs4[r] += pv;
            pk[r] = (__bf16)pv;
          }
          *(bf16x4*)&pt[w][SWZ64(lr, nf * 16 + lg * 4)] = pk;
        }
        float rs = (rs4[0] + rs4[1]) + (rs4[2] + rs4[3]);
        rs += __shfl_xor(rs, 16, 64);
        rs += __shfl_xor(rs, 32, 64);
        lsum[1] += rs;
      }

      // ---- PV: V-frags read once, feed both mf ----
#pragma unroll
      for (int kk = 0; kk < 2; ++kk) {
        bf16x8 pa1 = *(const bf16x8*)&pt[w][SWZ64(lr, kk * 32 + lg * 8)];
#pragma unroll
        for (int nf = 0; nf < 4; ++nf) {
          bf16x8 vf = *(const bf16x8*)&vt[par][SWZ64(nf * 16 + lr, kk * 32 + lg * 8)];
          apv[0][nf] = __builtin_amdgcn_mfma_f32_16x16x32_bf16(pa0[kk], vf, apv[0][nf], 0, 0, 0);
          apv[1][nf] = __builtin_amdgcn_mfma_f32_16x16x32_bf16(pa1, vf, apv[1][nf], 0, 0, 0);
        }
      }
    }

    // ---- merge pair states + memory term + write ----
    __syncthreads();
    float* dumpO  = (float*)&kt[0][0];                     // [64 q][64 d] fp32 = 16 KB
    __bf16* mt    = &vt[0][0];                             // memory^T [80][72] bf16
    float* dumpML = (float*)((char*)&vt[0][0] + 11520);    // m[64], l[64]
    if (par == 1) {
#pragma unroll
      for (int mf = 0; mf < 2; ++mf) {
#pragma unroll
        for (int nf = 0; nf < 4; ++nf)
#pragma unroll
          for (int r = 0; r < 4; ++r)
            dumpO[(qh * 32 + mf * 16 + lg * 4 + r) * 64 + nf * 16 + lr] = apv[mf][nf][r];
        dumpML[qh * 32 + mf * 16 + lr] = mrun[mf];
        dumpML[64 + qh * 32 + mf * 16 + lr] = lsum[mf];
      }
    } else {
      const int lt = tid;  // par0 waves are tid 0..127
      for (int i4 = lt; i4 < 1024; i4 += 128) {
        int d = i4 >> 4, e0 = (i4 & 15) * 4;
        float4 mv = *(const float4*)&memory[((size_t)hh * 64 + d) * 64 + e0];
        mt[(e0 + 0) * 72 + d] = (__bf16)mv.x;
        mt[(e0 + 1) * 72 + d] = (__bf16)mv.y;
        mt[(e0 + 2) * 72 + d] = (__bf16)mv.z;
        mt[(e0 + 3) * 72 + d] = (__bf16)mv.w;
      }
      for (int i = lt; i < 1024; i += 128) {
        int e = 64 + (i >> 6), d = i & 63;
        mt[e * 72 + d] = (__bf16)memnorm[hh * 64 + d];
      }
    }
    __syncthreads();

    if (par == 0) {
      // flash-merge (pair0 absorbs pair1)
      float lq[2][4], f1v[2], f2v[2];
#pragma unroll
      for (int mf = 0; mf < 2; ++mf) {
        float m2 = dumpML[qh * 32 + mf * 16 + lr];
        float l2 = dumpML[64 + qh * 32 + mf * 16 + lr];
        float m1 = mrun[mf];
        float fm = fmaxf(m1, m2);
        f1v[mf] = __builtin_amdgcn_exp2f(m1 - fm);
        f2v[mf] = __builtin_amdgcn_exp2f(m2 - fm);
        float lm = f1v[mf] * lsum[mf] + f2v[mf] * l2;
#pragma unroll
        for (int r = 0; r < 4; ++r) lq[mf][r] = __shfl(lm, (lg << 2) | r, 16);
      }
#pragma unroll
      for (int mf = 0; mf < 2; ++mf)
#pragma unroll
        for (int r = 0; r < 4; ++r) {
          float f1q = __shfl(f1v[mf], (lg << 2) | r, 16);
          float f2q = __shfl(f2v[mf], (lg << 2) | r, 16);
#pragma unroll
          for (int nf = 0; nf < 4; ++nf) {
            float o2 = dumpO[(qh * 32 + mf * 16 + lg * 4 + r) * 64 + nf * 16 + lr];
            apv[mf][nf][r] = f1q * apv[mf][nf][r] + f2q * o2;
          }
        }

      // sigma(Q) @ [M^T | norm]
      bf16x8 sf[2][2];
#pragma unroll
      for (int mf = 0; mf < 2; ++mf)
#pragma unroll
        for (int kk = 0; kk < 2; ++kk) {
          bf16x8 q = qf[mf][kk], s;
#pragma unroll
          for (int j = 0; j < 8; ++j) {
            float x = (float)q[j];
            float sg = x > 0.f ? x + 1.f : __builtin_amdgcn_exp2f(x * LOG2E);
            s[j] = (__bf16)sg;
          }
          sf[mf][kk] = s;
        }
      f32x4 am[2][5] = {};
#pragma unroll
      for (int kk = 0; kk < 2; ++kk)
#pragma unroll
        for (int nf = 0; nf < 5; ++nf) {
          bf16x8 bb = *(const bf16x8*)&mt[(nf * 16 + lr) * 72 + kk * 32 + lg * 8];
#pragma unroll
          for (int mf = 0; mf < 2; ++mf)
            am[mf][nf] = __builtin_amdgcn_mfma_f32_16x16x32_bf16(sf[mf][kk], bb, am[mf][nf], 0, 0, 0);
        }

#pragma unroll
      for (int mf = 0; mf < 2; ++mf) {
#pragma unroll
        for (int r = 0; r < 4; ++r) {
          int row = wq0 + mf * 16 + lg * 4 + r;
          float linv = __builtin_amdgcn_rcpf(lq[mf][r]);
          float nrm = fmaxf(am[mf][4][r], 1e-6f);
          float ninv = __builtin_amdgcn_rcpf(nrm);
          size_t base = ((size_t)b * 2048 + row) * 1024 + hh * 64;
#pragma unroll
          for (int nf = 0; nf < 4; ++nf)
            comb[base + nf * 16 + lr] =
                (__bf16)(gate * am[mf][nf][r] * ninv + og * apv[mf][nf][r] * linv);
        }
      }
    }
    __syncthreads();  // dumpO/mt reads done before next phase restages kt/vt
  }
}

// ---------------- launch ----------------
extern "C" void kernel_launch(void* const* d_in, const int* in_sizes, int n_in,
                              void* d_out, int out_size, void* d_ws, size_t ws_size,
                              hipStream_t stream) {
  const float* hs      = (const float*)d_in[0];
  const float* wq      = (const float*)d_in[1];
  const float* wk      = (const float*)d_in[2];
  const float* wv      = (const float*)d_in[3];
  const float* wo      = (const float*)d_in[4];
  const float* beta    = (const float*)d_in[5];
  const float* memory  = (const float*)d_in[6];
  const float* memnorm = (const float*)d_in[7];
  float* out = (float*)d_out;

  char* ws = (char*)d_ws;
  __bf16* hsb  = (__bf16*)(ws);                        // 8 MB  [4096][1024]
  __bf16* wqb  = (__bf16*)(ws + ((size_t)8  << 20));   // 2 MB
  __bf16* wkb  = (__bf16*)(ws + ((size_t)10 << 20));   // 2 MB
  __bf16* wvb  = (__bf16*)(ws + ((size_t)12 << 20));   // 2 MB
  __bf16* wob  = (__bf16*)(ws + ((size_t)14 << 20));   // 2 MB
  __bf16* qbuf = (__bf16*)(ws + ((size_t)16 << 20));   // 8 MB  [32][2048][64]
  __bf16* kbuf = (__bf16*)(ws + ((size_t)24 << 20));   // 8 MB
  __bf16* vtb  = (__bf16*)(ws + ((size_t)32 << 20));   // 8 MB  [32][64][2048]
  __bf16* comb = (__bf16*)(ws + ((size_t)40 << 20));   // 8 MB  [4096][1024]

  cvt_all<<<8192, 256, 0, stream>>>(hs, wq, wk, wv, wo, hsb, wqb, wkb, wvb, wob);

  qkv_gemm<<<768, 256, 0, stream>>>(hsb, wqb, wkb, wvb, qbuf, kbuf, vtb);

  attn_kernel<<<512, 256, 0, stream>>>(qbuf, kbuf, vtb, memory, memnorm, beta, comb);

  gemm_out<<<dim3(32, 16), 256, 0, stream>>>(comb, wob, out, 4096, 1024);
}

// Round 9
// 110.227 us; speedup vs baseline: 1.1082x; 1.1082x over previous
//
#include <hip/hip_runtime.h>
#include <stdint.h>

#define LOG2E 1.4426950408889634f

typedef __attribute__((ext_vector_type(8))) __bf16 bf16x8;
typedef __attribute__((ext_vector_type(4))) __bf16 bf16x4;
typedef __attribute__((ext_vector_type(4))) float f32x4;

__device__ inline void gll16(const void* g, void* l) {
  __builtin_amdgcn_global_load_lds(
      (const __attribute__((address_space(1))) void*)g,
      (__attribute__((address_space(3))) void*)l, 16, 0, 0);
}

// ---------------- fp32 -> bf16 conversion (all 5 tensors, one launch) ----------------
__global__ __launch_bounds__(256) void cvt_all(
    const float* __restrict__ hs, const float* __restrict__ wq,
    const float* __restrict__ wk, const float* __restrict__ wv,
    const float* __restrict__ wo,
    __bf16* __restrict__ hsb, __bf16* __restrict__ wqb, __bf16* __restrict__ wkb,
    __bf16* __restrict__ wvb, __bf16* __restrict__ wob) {
  int bid = blockIdx.x;
  const float* s; __bf16* d; int i;
  if (bid < 4096) { s = hs; d = hsb; i = bid * 256 + threadIdx.x; }
  else {
    int seg = (bid - 4096) >> 10;
    i = ((bid - 4096) & 1023) * 256 + threadIdx.x;
    s = seg == 0 ? wq : seg == 1 ? wk : seg == 2 ? wv : wo;
    d = seg == 0 ? wqb : seg == 1 ? wkb : seg == 2 ? wvb : wob;
  }
  float4 v = ((const float4*)s)[i];
  bf16x4 o;
  o[0] = (__bf16)v.x; o[1] = (__bf16)v.y; o[2] = (__bf16)v.z; o[3] = (__bf16)v.w;
  *(bf16x4*)&d[(size_t)i * 4] = o;
}

// ---------------- merged QKV projection GEMM ----------------
#define KSCALE 0.18033688011112042f  // HD^-0.5 * log2(e)
__global__ __launch_bounds__(256, 3) void qkv_gemm(
    const __bf16* __restrict__ hsb, const __bf16* __restrict__ wqb,
    const __bf16* __restrict__ wkb, const __bf16* __restrict__ wvb,
    __bf16* __restrict__ qbuf, __bf16* __restrict__ kbuf,
    __bf16* __restrict__ vtb) {
  constexpr int K = 1024;
  __shared__ __align__(16) __bf16 lta[128 * 32];
  __shared__ __align__(16) __bf16 ltb[128 * 32];
  const int bid = blockIdx.x;
  const int z = bid >> 8, r = bid & 255;
  const __bf16 *A, *Bt;
  int m0, n0;
  if (z < 2) {
    A = hsb; Bt = z ? wkb : wqb;
    m0 = (r & 31) * 128; n0 = (r >> 5) * 128;
  } else {
    A = wvb; Bt = hsb;
    m0 = (r & 7) * 128; n0 = (r >> 3) * 128;
  }
  const int tid = threadIdx.x;
  const int w = tid >> 6, l = tid & 63;
  const int lg = l >> 4, lr = l & 15;
  const int wm = (w >> 1) * 64, wn = (w & 1) * 64;
  f32x4 acc[4][4] = {};
  const int srow = w * 16 + (l >> 2);
  const int scol = (l & 3) * 8;
  const __bf16* ga = A + (size_t)(m0 + srow) * K + scol;
  const __bf16* gb = Bt + (size_t)(n0 + srow) * K + scol;
  __bf16* la = &lta[(size_t)w * 16 * 32];
  __bf16* lb = &ltb[(size_t)w * 16 * 32];
  for (int k0 = 0; k0 < K; k0 += 32) {
    __syncthreads();
    gll16(ga + k0, la);
    gll16(ga + 64 * K + k0, la + 64 * 32);
    gll16(gb + k0, lb);
    gll16(gb + 64 * K + k0, lb + 64 * 32);
    __syncthreads();
    bf16x8 af[4], bfr[4];
#pragma unroll
    for (int i = 0; i < 4; ++i) {
      af[i]  = *(const bf16x8*)&lta[(wm + i * 16 + lr) * 32 + lg * 8];
      bfr[i] = *(const bf16x8*)&ltb[(wn + i * 16 + lr) * 32 + lg * 8];
    }
#pragma unroll
    for (int i = 0; i < 4; ++i)
#pragma unroll
      for (int j = 0; j < 4; ++j)
        acc[i][j] = __builtin_amdgcn_mfma_f32_16x16x32_bf16(af[i], bfr[j], acc[i][j], 0, 0, 0);
  }
#pragma unroll
  for (int i = 0; i < 4; ++i)
#pragma unroll
    for (int j = 0; j < 4; ++j)
#pragma unroll
      for (int rr = 0; rr < 4; ++rr) {
        int gm = m0 + wm + i * 16 + lg * 4 + rr;
        int gn = n0 + wn + j * 16 + lr;
        float v = acc[i][j][rr];
        if (z < 2) {
          int bb = gm >> 11, s = gm & 2047, hh = gn >> 6, d = gn & 63;
          __bf16* dst = z ? kbuf : qbuf;
          if (z) v *= KSCALE;
          dst[(((size_t)bb * 16 + hh) * 2048 + s) * 64 + d] = (__bf16)v;
        } else {
          int bb = gn >> 11, s = gn & 2047, hh = gm >> 6, d = gm & 63;
          vtb[(((size_t)bb * 16 + hh) * 64 + d) * 2048 + s] = (__bf16)v;
        }
      }
}

// ---------------- output GEMM: 128x64 tiles -> 512 blocks (2/CU) ----------------
__global__ __launch_bounds__(256, 2) void gemm_out(const __bf16* __restrict__ A,
                                                   const __bf16* __restrict__ Bt,
                                                   float* __restrict__ C,
                                                   int M, int N) {
  constexpr int K = 1024;
  __shared__ __align__(16) __bf16 lta[128 * 32];
  __shared__ __align__(16) __bf16 ltb[64 * 32];
  const int tid = threadIdx.x;
  const int w = tid >> 6, l = tid & 63;
  const int lg = l >> 4, lr = l & 15;
  const int m0 = blockIdx.x * 128, n0 = blockIdx.y * 64;
  const int wm = (w >> 1) * 64, wn = (w & 1) * 32;
  f32x4 acc[4][2] = {};
  const int srow = tid >> 2;          // 0..63
  const int scol = (tid & 3) * 8;
  const __bf16* ga = A + (size_t)(m0 + srow) * K + scol;
  const __bf16* gb = Bt + (size_t)(n0 + srow) * K + scol;
  __bf16* la = &lta[(size_t)w * 512];
  __bf16* lb = &ltb[(size_t)w * 512];
  for (int k0 = 0; k0 < K; k0 += 32) {
    __syncthreads();
    gll16(ga + k0, la);
    gll16(ga + (size_t)64 * K + k0, la + 64 * 32);
    gll16(gb + k0, lb);
    __syncthreads();
    bf16x8 af[4], bfr[2];
#pragma unroll
    for (int i = 0; i < 4; ++i)
      af[i]  = *(const bf16x8*)&lta[(wm + i * 16 + lr) * 32 + lg * 8];
#pragma unroll
    for (int j = 0; j < 2; ++j)
      bfr[j] = *(const bf16x8*)&ltb[(wn + j * 16 + lr) * 32 + lg * 8];
#pragma unroll
    for (int i = 0; i < 4; ++i)
#pragma unroll
      for (int j = 0; j < 2; ++j)
        acc[i][j] = __builtin_amdgcn_mfma_f32_16x16x32_bf16(af[i], bfr[j], acc[i][j], 0, 0, 0);
  }
#pragma unroll
  for (int i = 0; i < 4; ++i)
#pragma unroll
    for (int j = 0; j < 2; ++j)
#pragma unroll
      for (int rr = 0; rr < 4; ++rr) {
        int gm = m0 + wm + i * 16 + lg * 4 + rr;
        int gn = n0 + wn + j * 16 + lr;
        C[(size_t)gm * N + gn] = acc[i][j][rr];
      }
}

// ---------------- attention + memory retrieval ----------------
// 1024 blocks: t = 31-(bx>>5) (big-first), bh = bx&31. 64-row q-tiles,
// 4 waves x 16 rows. Swapped QK^T (lane owns q-row lr), softmax in exp2
// domain (K pre-scaled). KV128 tiles staged via global_load_lds with
// pre-swizzled global source into XOR-swizzled LDS. P never touches LDS:
// cvt_pk + permlane32_swap + shfl_xor(16) redistribute P from D-layout to
// the PV A-fragment layout in registers (mapping verified: lane&15 = q
// preserved; k = 32kk+8lg+j reproduced). LDS 32 KB -> 5 blocks/CU.
#define DEFER_THR 11.5f
#define SWZ(row, col) (((row) << 7) + ((col) ^ (((row) & 7) << 3)))   // stride 128
#define SWZK(row, col) (((row) << 6) + ((col) ^ (((row) & 7) << 3)))  // stride 64

__global__ __launch_bounds__(256, 5) void attn_kernel(
    const __bf16* __restrict__ qb,    // [32][2048][64]
    const __bf16* __restrict__ kb,    // [32][2048][64] (pre-scaled)
    const __bf16* __restrict__ vtb,   // [32][64][2048]
    const float* __restrict__ memory, // [16][64][64]
    const float* __restrict__ memnorm,// [16][64]
    const float* __restrict__ beta,   // [16]
    __bf16* __restrict__ comb)        // [4096][1024]
{
  __shared__ __align__(16) __bf16 kt[128 * 64];   // 16 KB (reused as mt)
  __shared__ __align__(16) __bf16 vt[64 * 128];   // 16 KB  -> 32 KB total

  const int tid = threadIdx.x;
  const int w = tid >> 6, l = tid & 63;
  const int lg = l >> 4, lr = l & 15;
  const int t = 31 - (blockIdx.x >> 5);
  const int bh = blockIdx.x & 31;
  const int hh = bh & 15, b = bh >> 4;
  const int wq0 = t * 64 + w * 16;
  const int ntiles = (t >> 1) + 1;

  // staging: pre-swizzled global source columns, linear LDS dest (R6-proven).
  const int k_row = tid >> 3;                          // 0..31
  const int k_col = ((tid & 7) ^ (k_row & 7)) * 8;
  const __bf16* ksrc = kb + ((size_t)bh * 2048 + k_row) * 64 + k_col;
  const int v_d = tid >> 4;                            // 0..15
  const int v_col = ((tid & 15) ^ (v_d & 7)) * 8;
  const __bf16* vsrc = vtb + ((size_t)bh * 64 + v_d) * 2048 + v_col;
  __bf16* kdst = &kt[w * 512];
  __bf16* vdst = &vt[w * 512];

  // ---- Q fragments (per-lane: row/col = lr, k = kk*32 + lg*8 + j) ----
  bf16x8 qf[2];
#pragma unroll
  for (int kk = 0; kk < 2; ++kk)
    qf[kk] = *(const bf16x8*)(qb + ((size_t)bh * 2048 + wq0 + lr) * 64 + kk * 32 + lg * 8);

  float mrun = -1e30f, lsum = 0.f;
  f32x4 apv[4] = {};

  for (int kv = 0; kv < ntiles; ++kv) {
    const int kv0 = kv * 128;
    __syncthreads();
#pragma unroll
    for (int i = 0; i < 4; ++i) {
      gll16(ksrc + (size_t)(kv0 + i * 32) * 64, kdst + i * 2048);
      gll16(vsrc + (size_t)i * 16 * 2048 + kv0, vdst + i * 2048);
    }
    __syncthreads();   // drains vmcnt -> tiles ready

    // ---- QK^T swapped: sc[nf]: k = kv0+nf*16+lg*4+r, q = wq0+lr ----
    f32x4 sc[8] = {};
#pragma unroll
    for (int kk = 0; kk < 2; ++kk)
#pragma unroll
      for (int nf = 0; nf < 8; ++nf) {
        bf16x8 kf = *(const bf16x8*)&kt[SWZK(nf * 16 + lr, kk * 32 + lg * 8)];
        sc[nf] = __builtin_amdgcn_mfma_f32_16x16x32_bf16(kf, qf[kk], sc[nf], 0, 0, 0);
      }

    // ---- causal mask (only last KV tile can touch the diagonal) ----
    const int qrow = wq0 + lr;
    if (kv == ntiles - 1) {
#pragma unroll
      for (int nf = 0; nf < 8; ++nf)
#pragma unroll
        for (int r = 0; r < 4; ++r)
          if (kv0 + nf * 16 + lg * 4 + r > qrow) sc[nf][r] = -1e30f;
    }

    // ---- in-lane max + 2-shuffle reduce ----
    f32x4 m4 = sc[0];
#pragma unroll
    for (int nf = 1; nf < 8; ++nf)
#pragma unroll
      for (int r = 0; r < 4; ++r) m4[r] = fmaxf(m4[r], sc[nf][r]);
    float mx = fmaxf(fmaxf(m4[0], m4[1]), fmaxf(m4[2], m4[3]));
    mx = fmaxf(mx, __shfl_xor(mx, 16, 64));
    mx = fmaxf(mx, __shfl_xor(mx, 32, 64));

    // ---- defer-max rescale ----
    if (!__all(mx - mrun <= DEFER_THR)) {
      float mold = mrun;
      float mn = fmaxf(mold, mx);
      mrun = mn;
      float scl = __builtin_amdgcn_exp2f(mold - mn);
      lsum *= scl;
      float sclq[4];
#pragma unroll
      for (int r = 0; r < 4; ++r) sclq[r] = __shfl(scl, (lg << 2) | r, 16);
#pragma unroll
      for (int nf = 0; nf < 4; ++nf)
#pragma unroll
        for (int r = 0; r < 4; ++r) apv[nf][r] *= sclq[r];
    }

    // ---- P = exp2(S - m) in place + row-sum ----
    f32x4 rs4 = {0.f, 0.f, 0.f, 0.f};
#pragma unroll
    for (int nf = 0; nf < 8; ++nf)
#pragma unroll
      for (int r = 0; r < 4; ++r) {
        float pv = __builtin_amdgcn_exp2f(sc[nf][r] - mrun);
        sc[nf][r] = pv;
        rs4[r] += pv;
      }
    float rs = (rs4[0] + rs4[1]) + (rs4[2] + rs4[3]);
    rs += __shfl_xor(rs, 16, 64);
    rs += __shfl_xor(rs, 32, 64);
    lsum += rs;

    // ---- in-register P redistribution + PV ----
    // Lane holds P[q=lr][k=16nf+4lg+r]; PA[kk] needs P[q=lr][k=32kk+8lg+j].
    // Per kk: 4 cvt_pk -> words W[2kk|2kk+1][h]; permlane32_swap pairs
    // (x'={A.lo,B.lo}, y'={A.hi,B.hi}); shfl_xor16 + select by lg&1.
#pragma unroll
    for (int kk = 0; kk < 4; ++kk) {
      uint32_t a0, a1, b0, b1;
      asm("v_cvt_pk_bf16_f32 %0, %1, %2" : "=v"(a0) : "v"(sc[2 * kk][0]), "v"(sc[2 * kk][1]));
      asm("v_cvt_pk_bf16_f32 %0, %1, %2" : "=v"(a1) : "v"(sc[2 * kk][2]), "v"(sc[2 * kk][3]));
      asm("v_cvt_pk_bf16_f32 %0, %1, %2" : "=v"(b0) : "v"(sc[2 * kk + 1][0]), "v"(sc[2 * kk + 1][1]));
      asm("v_cvt_pk_bf16_f32 %0, %1, %2" : "=v"(b1) : "v"(sc[2 * kk + 1][2]), "v"(sc[2 * kk + 1][3]));
      asm("v_permlane32_swap_b32 %0, %1" : "+v"(a0), "+v"(b0));
      asm("v_permlane32_swap_b32 %0, %1" : "+v"(a1), "+v"(b1));
      uint32_t sx0 = (uint32_t)__shfl_xor((int)a0, 16, 64);
      uint32_t sy0 = (uint32_t)__shfl_xor((int)b0, 16, 64);
      uint32_t sx1 = (uint32_t)__shfl_xor((int)a1, 16, 64);
      uint32_t sy1 = (uint32_t)__shfl_xor((int)b1, 16, 64);
      const bool odd = (lg & 1);
      union { uint32_t u[4]; bf16x8 v; } pa;
      pa.u[0] = odd ? sy0 : a0;
      pa.u[1] = odd ? sy1 : a1;
      pa.u[2] = odd ? b0 : sx0;
      pa.u[3] = odd ? b1 : sx1;
#pragma unroll
      for (int nf = 0; nf < 4; ++nf) {
        bf16x8 vf = *(const bf16x8*)&vt[SWZ(nf * 16 + lr, kk * 32 + lg * 8)];
        apv[nf] = __builtin_amdgcn_mfma_f32_16x16x32_bf16(pa.v, vf, apv[nf], 0, 0, 0);
      }
    }
  }

  // ---- memory retrieval: sigma(Q) @ [M^T | mn replicated] via MFMA ----
  __syncthreads();  // all waves done with kt reads
  __bf16* mt = kt;  // reuse kt region for memory^T [80][72]
  for (int i = tid; i < 64 * 64; i += 256) {
    int d = i >> 6, e = i & 63;
    mt[e * 72 + d] = (__bf16)memory[((size_t)hh * 64 + d) * 64 + e];
  }
  for (int i = tid; i < 16 * 64; i += 256) {
    int e = 64 + (i >> 6), d = i & 63;
    mt[e * 72 + d] = (__bf16)memnorm[hh * 64 + d];
  }
  __syncthreads();

  bf16x8 sf[2];
#pragma unroll
  for (int kk = 0; kk < 2; ++kk) {
    bf16x8 q = qf[kk], s;
#pragma unroll
    for (int j = 0; j < 8; ++j) {
      float x = (float)q[j];
      float sg = x > 0.f ? x + 1.f : __builtin_amdgcn_exp2f(x * LOG2E);
      s[j] = (__bf16)sg;
    }
    sf[kk] = s;
  }

  f32x4 am[5] = {};
#pragma unroll
  for (int kk = 0; kk < 2; ++kk)
#pragma unroll
    for (int nf = 0; nf < 5; ++nf) {
      bf16x8 bb = *(const bf16x8*)&mt[(nf * 16 + lr) * 72 + kk * 32 + lg * 8];
      am[nf] = __builtin_amdgcn_mfma_f32_16x16x32_bf16(sf[kk], bb, am[nf], 0, 0, 0);
    }

  // ---- combine + write ----
  const float gate = 1.f / (1.f + __builtin_amdgcn_exp2f(-beta[hh] * LOG2E));
  const float og = 1.f - gate;
  float lsq[4];
#pragma unroll
  for (int r = 0; r < 4; ++r) lsq[r] = __shfl(lsum, (lg << 2) | r, 16);
#pragma unroll
  for (int r = 0; r < 4; ++r) {
    int row = wq0 + lg * 4 + r;
    float linv = __builtin_amdgcn_rcpf(lsq[r]);
    float nrm = fmaxf(am[4][r], 1e-6f);
    float ninv = __builtin_amdgcn_rcpf(nrm);
    size_t base = ((size_t)b * 2048 + row) * 1024 + hh * 64;
#pragma unroll
    for (int nf = 0; nf < 4; ++nf) {
      float al = apv[nf][r] * linv;
      float amv = am[nf][r] * ninv;
      comb[base + nf * 16 + lr] = (__bf16)(gate * amv + og * al);
    }
  }
}

// ---------------- launch ----------------
extern "C" void kernel_launch(void* const* d_in, const int* in_sizes, int n_in,
                              void* d_out, int out_size, void* d_ws, size_t ws_size,
                              hipStream_t stream) {
  const float* hs      = (const float*)d_in[0];
  const float* wq      = (const float*)d_in[1];
  const float* wk      = (const float*)d_in[2];
  const float* wv      = (const float*)d_in[3];
  const float* wo      = (const float*)d_in[4];
  const float* beta    = (const float*)d_in[5];
  const float* memory  = (const float*)d_in[6];
  const float* memnorm = (const float*)d_in[7];
  float* out = (float*)d_out;

  char* ws = (char*)d_ws;
  __bf16* hsb  = (__bf16*)(ws);                        // 8 MB  [4096][1024]
  __bf16* wqb  = (__bf16*)(ws + ((size_t)8  << 20));   // 2 MB
  __bf16* wkb  = (__bf16*)(ws + ((size_t)10 << 20));   // 2 MB
  __bf16* wvb  = (__bf16*)(ws + ((size_t)12 << 20));   // 2 MB
  __bf16* wob  = (__bf16*)(ws + ((size_t)14 << 20));   // 2 MB
  __bf16* qbuf = (__bf16*)(ws + ((size_t)16 << 20));   // 8 MB  [32][2048][64]
  __bf16* kbuf = (__bf16*)(ws + ((size_t)24 << 20));   // 8 MB
  __bf16* vtb  = (__bf16*)(ws + ((size_t)32 << 20));   // 8 MB  [32][64][2048]
  __bf16* comb = (__bf16*)(ws + ((size_t)40 << 20));   // 8 MB  [4096][1024]

  cvt_all<<<8192, 256, 0, stream>>>(hs, wq, wk, wv, wo, hsb, wqb, wkb, wvb, wob);

  qkv_gemm<<<768, 256, 0, stream>>>(hsb, wqb, wkb, wvb, qbuf, kbuf, vtb);

  attn_kernel<<<1024, 256, 0, stream>>>(qbuf, kbuf, vtb, memory, memnorm, beta, comb);

  gemm_out<<<dim3(32, 16), 256, 0, stream>>>(comb, wob, out, 4096, 1024);
}

// Round 10
// 104.326 us; speedup vs baseline: 1.1709x; 1.0566x over previous
//
#include <hip/hip_runtime.h>
#include <stdint.h>

#define LOG2E 1.4426950408889634f

typedef __attribute__((ext_vector_type(8))) __bf16 bf16x8;
typedef __attribute__((ext_vector_type(4))) __bf16 bf16x4;
typedef __attribute__((ext_vector_type(4))) float f32x4;

__device__ inline void gll16(const void* g, void* l) {
  __builtin_amdgcn_global_load_lds(
      (const __attribute__((address_space(1))) void*)g,
      (__attribute__((address_space(3))) void*)l, 16, 0, 0);
}

// ---------------- fp32 -> bf16 conversion (all 5 tensors, one launch) ----------------
__global__ __launch_bounds__(256) void cvt_all(
    const float* __restrict__ hs, const float* __restrict__ wq,
    const float* __restrict__ wk, const float* __restrict__ wv,
    const float* __restrict__ wo,
    __bf16* __restrict__ hsb, __bf16* __restrict__ wqb, __bf16* __restrict__ wkb,
    __bf16* __restrict__ wvb, __bf16* __restrict__ wob) {
  int bid = blockIdx.x;
  const float* s; __bf16* d; int i;
  if (bid < 4096) { s = hs; d = hsb; i = bid * 256 + threadIdx.x; }
  else {
    int seg = (bid - 4096) >> 10;
    i = ((bid - 4096) & 1023) * 256 + threadIdx.x;
    s = seg == 0 ? wq : seg == 1 ? wk : seg == 2 ? wv : wo;
    d = seg == 0 ? wqb : seg == 1 ? wkb : seg == 2 ? wvb : wob;
  }
  float4 v = ((const float4*)s)[i];
  bf16x4 o;
  o[0] = (__bf16)v.x; o[1] = (__bf16)v.y; o[2] = (__bf16)v.z; o[3] = (__bf16)v.w;
  *(bf16x4*)&d[(size_t)i * 4] = o;
}

// ---------------- merged QKV projection GEMM ----------------
#define KSCALE 0.18033688011112042f  // HD^-0.5 * log2(e)
__global__ __launch_bounds__(256, 3) void qkv_gemm(
    const __bf16* __restrict__ hsb, const __bf16* __restrict__ wqb,
    const __bf16* __restrict__ wkb, const __bf16* __restrict__ wvb,
    __bf16* __restrict__ qbuf, __bf16* __restrict__ kbuf,
    __bf16* __restrict__ vtb) {
  constexpr int K = 1024;
  __shared__ __align__(16) __bf16 lta[128 * 32];
  __shared__ __align__(16) __bf16 ltb[128 * 32];
  const int bid = blockIdx.x;
  const int z = bid >> 8, r = bid & 255;
  const __bf16 *A, *Bt;
  int m0, n0;
  if (z < 2) {
    A = hsb; Bt = z ? wkb : wqb;
    m0 = (r & 31) * 128; n0 = (r >> 5) * 128;
  } else {
    A = wvb; Bt = hsb;
    m0 = (r & 7) * 128; n0 = (r >> 3) * 128;
  }
  const int tid = threadIdx.x;
  const int w = tid >> 6, l = tid & 63;
  const int lg = l >> 4, lr = l & 15;
  const int wm = (w >> 1) * 64, wn = (w & 1) * 64;
  f32x4 acc[4][4] = {};
  const int srow = w * 16 + (l >> 2);
  const int scol = (l & 3) * 8;
  const __bf16* ga = A + (size_t)(m0 + srow) * K + scol;
  const __bf16* gb = Bt + (size_t)(n0 + srow) * K + scol;
  __bf16* la = &lta[(size_t)w * 16 * 32];
  __bf16* lb = &ltb[(size_t)w * 16 * 32];
  for (int k0 = 0; k0 < K; k0 += 32) {
    __syncthreads();
    gll16(ga + k0, la);
    gll16(ga + 64 * K + k0, la + 64 * 32);
    gll16(gb + k0, lb);
    gll16(gb + 64 * K + k0, lb + 64 * 32);
    __syncthreads();
    bf16x8 af[4], bfr[4];
#pragma unroll
    for (int i = 0; i < 4; ++i) {
      af[i]  = *(const bf16x8*)&lta[(wm + i * 16 + lr) * 32 + lg * 8];
      bfr[i] = *(const bf16x8*)&ltb[(wn + i * 16 + lr) * 32 + lg * 8];
    }
#pragma unroll
    for (int i = 0; i < 4; ++i)
#pragma unroll
      for (int j = 0; j < 4; ++j)
        acc[i][j] = __builtin_amdgcn_mfma_f32_16x16x32_bf16(af[i], bfr[j], acc[i][j], 0, 0, 0);
  }
#pragma unroll
  for (int i = 0; i < 4; ++i)
#pragma unroll
    for (int j = 0; j < 4; ++j)
#pragma unroll
      for (int rr = 0; rr < 4; ++rr) {
        int gm = m0 + wm + i * 16 + lg * 4 + rr;
        int gn = n0 + wn + j * 16 + lr;
        float v = acc[i][j][rr];
        if (z < 2) {
          int bb = gm >> 11, s = gm & 2047, hh = gn >> 6, d = gn & 63;
          __bf16* dst = z ? kbuf : qbuf;
          if (z) v *= KSCALE;
          dst[(((size_t)bb * 16 + hh) * 2048 + s) * 64 + d] = (__bf16)v;
        } else {
          int bb = gn >> 11, s = gn & 2047, hh = gm >> 6, d = gm & 63;
          vtb[(((size_t)bb * 16 + hh) * 64 + d) * 2048 + s] = (__bf16)v;
        }
      }
}

// ---------------- output GEMM: 128x64 tiles -> 512 blocks (2/CU) ----------------
__global__ __launch_bounds__(256, 2) void gemm_out(const __bf16* __restrict__ A,
                                                   const __bf16* __restrict__ Bt,
                                                   float* __restrict__ C,
                                                   int M, int N) {
  constexpr int K = 1024;
  __shared__ __align__(16) __bf16 lta[128 * 32];
  __shared__ __align__(16) __bf16 ltb[64 * 32];
  const int tid = threadIdx.x;
  const int w = tid >> 6, l = tid & 63;
  const int lg = l >> 4, lr = l & 15;
  const int m0 = blockIdx.x * 128, n0 = blockIdx.y * 64;
  const int wm = (w >> 1) * 64, wn = (w & 1) * 32;
  f32x4 acc[4][2] = {};
  const int srow = tid >> 2;          // 0..63
  const int scol = (tid & 3) * 8;
  const __bf16* ga = A + (size_t)(m0 + srow) * K + scol;
  const __bf16* gb = Bt + (size_t)(n0 + srow) * K + scol;
  __bf16* la = &lta[(size_t)w * 512];
  __bf16* lb = &ltb[(size_t)w * 512];
  for (int k0 = 0; k0 < K; k0 += 32) {
    __syncthreads();
    gll16(ga + k0, la);
    gll16(ga + (size_t)64 * K + k0, la + 64 * 32);
    gll16(gb + k0, lb);
    __syncthreads();
    bf16x8 af[4], bfr[2];
#pragma unroll
    for (int i = 0; i < 4; ++i)
      af[i]  = *(const bf16x8*)&lta[(wm + i * 16 + lr) * 32 + lg * 8];
#pragma unroll
    for (int j = 0; j < 2; ++j)
      bfr[j] = *(const bf16x8*)&ltb[(wn + j * 16 + lr) * 32 + lg * 8];
#pragma unroll
    for (int i = 0; i < 4; ++i)
#pragma unroll
      for (int j = 0; j < 2; ++j)
        acc[i][j] = __builtin_amdgcn_mfma_f32_16x16x32_bf16(af[i], bfr[j], acc[i][j], 0, 0, 0);
  }
#pragma unroll
  for (int i = 0; i < 4; ++i)
#pragma unroll
    for (int j = 0; j < 2; ++j)
#pragma unroll
      for (int rr = 0; rr < 4; ++rr) {
        int gm = m0 + wm + i * 16 + lg * 4 + rr;
        int gn = n0 + wn + j * 16 + lr;
        C[(size_t)gm * N + gn] = acc[i][j][rr];
      }
}

// ---------------- attention + memory retrieval ----------------
// 1024 blocks: t = 31-(bx>>5) (big-first), bh = bx&31. 64-row q-tiles,
// 4 waves x 16 rows. Swapped QK^T (lane owns q-row lr), softmax in exp2
// domain (K pre-scaled). KV128 tiles staged via global_load_lds with
// pre-swizzled global source into XOR-swizzled LDS. P never touches LDS:
// per kk, 4 cvt_pk + 2 permlane32_swap + 2 permlane16_swap produce the PV
// A-fragment entirely on the VALU pipe (element-wise verified:
// permlane32 pairs the 32-halves, permlane16 then delivers u0/u2 exactly).
// LDS 32 KB -> 5 blocks/CU.
#define DEFER_THR 11.5f
#define SWZ(row, col) (((row) << 7) + ((col) ^ (((row) & 7) << 3)))   // stride 128
#define SWZK(row, col) (((row) << 6) + ((col) ^ (((row) & 7) << 3)))  // stride 64

__global__ __launch_bounds__(256, 5) void attn_kernel(
    const __bf16* __restrict__ qb,    // [32][2048][64]
    const __bf16* __restrict__ kb,    // [32][2048][64] (pre-scaled)
    const __bf16* __restrict__ vtb,   // [32][64][2048]
    const float* __restrict__ memory, // [16][64][64]
    const float* __restrict__ memnorm,// [16][64]
    const float* __restrict__ beta,   // [16]
    __bf16* __restrict__ comb)        // [4096][1024]
{
  __shared__ __align__(16) __bf16 kt[128 * 64];   // 16 KB (reused as mt)
  __shared__ __align__(16) __bf16 vt[64 * 128];   // 16 KB  -> 32 KB total

  const int tid = threadIdx.x;
  const int w = tid >> 6, l = tid & 63;
  const int lg = l >> 4, lr = l & 15;
  const int t = 31 - (blockIdx.x >> 5);
  const int bh = blockIdx.x & 31;
  const int hh = bh & 15, b = bh >> 4;
  const int wq0 = t * 64 + w * 16;
  const int ntiles = (t >> 1) + 1;

  // staging: pre-swizzled global source columns, linear LDS dest (R6-proven).
  const int k_row = tid >> 3;                          // 0..31
  const int k_col = ((tid & 7) ^ (k_row & 7)) * 8;
  const __bf16* ksrc = kb + ((size_t)bh * 2048 + k_row) * 64 + k_col;
  const int v_d = tid >> 4;                            // 0..15
  const int v_col = ((tid & 15) ^ (v_d & 7)) * 8;
  const __bf16* vsrc = vtb + ((size_t)bh * 64 + v_d) * 2048 + v_col;
  __bf16* kdst = &kt[w * 512];
  __bf16* vdst = &vt[w * 512];

  // ---- Q fragments (per-lane: row/col = lr, k = kk*32 + lg*8 + j) ----
  bf16x8 qf[2];
#pragma unroll
  for (int kk = 0; kk < 2; ++kk)
    qf[kk] = *(const bf16x8*)(qb + ((size_t)bh * 2048 + wq0 + lr) * 64 + kk * 32 + lg * 8);

  float mrun = -1e30f, lsum = 0.f;
  f32x4 apv[4] = {};

  for (int kv = 0; kv < ntiles; ++kv) {
    const int kv0 = kv * 128;
    __syncthreads();
#pragma unroll
    for (int i = 0; i < 4; ++i) {
      gll16(ksrc + (size_t)(kv0 + i * 32) * 64, kdst + i * 2048);
      gll16(vsrc + (size_t)i * 16 * 2048 + kv0, vdst + i * 2048);
    }
    __syncthreads();   // drains vmcnt -> tiles ready

    // ---- QK^T swapped: sc[nf]: k = kv0+nf*16+lg*4+r, q = wq0+lr ----
    f32x4 sc[8] = {};
#pragma unroll
    for (int kk = 0; kk < 2; ++kk)
#pragma unroll
      for (int nf = 0; nf < 8; ++nf) {
        bf16x8 kf = *(const bf16x8*)&kt[SWZK(nf * 16 + lr, kk * 32 + lg * 8)];
        sc[nf] = __builtin_amdgcn_mfma_f32_16x16x32_bf16(kf, qf[kk], sc[nf], 0, 0, 0);
      }

    // ---- causal mask (only last KV tile can touch the diagonal) ----
    const int qrow = wq0 + lr;
    if (kv == ntiles - 1) {
#pragma unroll
      for (int nf = 0; nf < 8; ++nf)
#pragma unroll
        for (int r = 0; r < 4; ++r)
          if (kv0 + nf * 16 + lg * 4 + r > qrow) sc[nf][r] = -1e30f;
    }

    // ---- in-lane max + 2-shuffle reduce ----
    f32x4 m4 = sc[0];
#pragma unroll
    for (int nf = 1; nf < 8; ++nf)
#pragma unroll
      for (int r = 0; r < 4; ++r) m4[r] = fmaxf(m4[r], sc[nf][r]);
    float mx = fmaxf(fmaxf(m4[0], m4[1]), fmaxf(m4[2], m4[3]));
    mx = fmaxf(mx, __shfl_xor(mx, 16, 64));
    mx = fmaxf(mx, __shfl_xor(mx, 32, 64));

    // ---- defer-max rescale ----
    if (!__all(mx - mrun <= DEFER_THR)) {
      float mold = mrun;
      float mn = fmaxf(mold, mx);
      mrun = mn;
      float scl = __builtin_amdgcn_exp2f(mold - mn);
      lsum *= scl;
      float sclq[4];
#pragma unroll
      for (int r = 0; r < 4; ++r) sclq[r] = __shfl(scl, (lg << 2) | r, 16);
#pragma unroll
      for (int nf = 0; nf < 4; ++nf)
#pragma unroll
        for (int r = 0; r < 4; ++r) apv[nf][r] *= sclq[r];
    }

    // ---- P = exp2(S - m) in place + row-sum ----
    f32x4 rs4 = {0.f, 0.f, 0.f, 0.f};
#pragma unroll
    for (int nf = 0; nf < 8; ++nf)
#pragma unroll
      for (int r = 0; r < 4; ++r) {
        float pv = __builtin_amdgcn_exp2f(sc[nf][r] - mrun);
        sc[nf][r] = pv;
        rs4[r] += pv;
      }
    float rs = (rs4[0] + rs4[1]) + (rs4[2] + rs4[3]);
    rs += __shfl_xor(rs, 16, 64);
    rs += __shfl_xor(rs, 32, 64);
    lsum += rs;

    // ---- in-register P redistribution (pure VALU) + PV ----
    // Lane holds P[q=lr][k=16nf+4lg+r]; PA[kk] needs P[q=lr][k=32kk+8lg+j].
    // Step 1: a=cvt_pk(sc[2kk]), b=cvt_pk(sc[2kk+1]).
    // Step 2: permlane32_swap(a,b): a' = {a.lo32 | b.lo32}, b' = {a.hi32 | b.hi32}.
    // Step 3: permlane16_swap(a',b'): first output = u0/u1, second = u2/u3.
#pragma unroll
    for (int kk = 0; kk < 4; ++kk) {
      uint32_t a0, a1, b0, b1;
      asm("v_cvt_pk_bf16_f32 %0, %1, %2" : "=v"(a0) : "v"(sc[2 * kk][0]), "v"(sc[2 * kk][1]));
      asm("v_cvt_pk_bf16_f32 %0, %1, %2" : "=v"(a1) : "v"(sc[2 * kk][2]), "v"(sc[2 * kk][3]));
      asm("v_cvt_pk_bf16_f32 %0, %1, %2" : "=v"(b0) : "v"(sc[2 * kk + 1][0]), "v"(sc[2 * kk + 1][1]));
      asm("v_cvt_pk_bf16_f32 %0, %1, %2" : "=v"(b1) : "v"(sc[2 * kk + 1][2]), "v"(sc[2 * kk + 1][3]));
      asm("v_permlane32_swap_b32 %0, %1" : "+v"(a0), "+v"(b0));
      asm("v_permlane32_swap_b32 %0, %1" : "+v"(a1), "+v"(b1));
      asm("v_permlane16_swap_b32 %0, %1" : "+v"(a0), "+v"(b0));
      asm("v_permlane16_swap_b32 %0, %1" : "+v"(a1), "+v"(b1));
      union { uint32_t u[4]; bf16x8 v; } pa;
      pa.u[0] = a0;   // k = 8lg + {0,1}
      pa.u[1] = a1;   // k = 8lg + {2,3}
      pa.u[2] = b0;   // k = 8lg + {4,5}
      pa.u[3] = b1;   // k = 8lg + {6,7}
#pragma unroll
      for (int nf = 0; nf < 4; ++nf) {
        bf16x8 vf = *(const bf16x8*)&vt[SWZ(nf * 16 + lr, kk * 32 + lg * 8)];
        apv[nf] = __builtin_amdgcn_mfma_f32_16x16x32_bf16(pa.v, vf, apv[nf], 0, 0, 0);
      }
    }
  }

  // ---- memory retrieval: sigma(Q) @ [M^T | mn replicated] via MFMA ----
  __syncthreads();  // all waves done with kt reads
  __bf16* mt = kt;  // reuse kt region for memory^T [80][72]
  for (int i = tid; i < 64 * 64; i += 256) {
    int d = i >> 6, e = i & 63;
    mt[e * 72 + d] = (__bf16)memory[((size_t)hh * 64 + d) * 64 + e];
  }
  for (int i = tid; i < 16 * 64; i += 256) {
    int e = 64 + (i >> 6), d = i & 63;
    mt[e * 72 + d] = (__bf16)memnorm[hh * 64 + d];
  }
  __syncthreads();

  bf16x8 sf[2];
#pragma unroll
  for (int kk = 0; kk < 2; ++kk) {
    bf16x8 q = qf[kk], s;
#pragma unroll
    for (int j = 0; j < 8; ++j) {
      float x = (float)q[j];
      float sg = x > 0.f ? x + 1.f : __builtin_amdgcn_exp2f(x * LOG2E);
      s[j] = (__bf16)sg;
    }
    sf[kk] = s;
  }

  f32x4 am[5] = {};
#pragma unroll
  for (int kk = 0; kk < 2; ++kk)
#pragma unroll
    for (int nf = 0; nf < 5; ++nf) {
      bf16x8 bb = *(const bf16x8*)&mt[(nf * 16 + lr) * 72 + kk * 32 + lg * 8];
      am[nf] = __builtin_amdgcn_mfma_f32_16x16x32_bf16(sf[kk], bb, am[nf], 0, 0, 0);
    }

  // ---- combine + write ----
  const float gate = 1.f / (1.f + __builtin_amdgcn_exp2f(-beta[hh] * LOG2E));
  const float og = 1.f - gate;
  float lsq[4];
#pragma unroll
  for (int r = 0; r < 4; ++r) lsq[r] = __shfl(lsum, (lg << 2) | r, 16);
#pragma unroll
  for (int r = 0; r < 4; ++r) {
    int row = wq0 + lg * 4 + r;
    float linv = __builtin_amdgcn_rcpf(lsq[r]);
    float nrm = fmaxf(am[4][r], 1e-6f);
    float ninv = __builtin_amdgcn_rcpf(nrm);
    size_t base = ((size_t)b * 2048 + row) * 1024 + hh * 64;
#pragma unroll
    for (int nf = 0; nf < 4; ++nf) {
      float al = apv[nf][r] * linv;
      float amv = am[nf][r] * ninv;
      comb[base + nf * 16 + lr] = (__bf16)(gate * amv + og * al);
    }
  }
}

// ---------------- launch ----------------
extern "C" void kernel_launch(void* const* d_in, const int* in_sizes, int n_in,
                              void* d_out, int out_size, void* d_ws, size_t ws_size,
                              hipStream_t stream) {
  const float* hs      = (const float*)d_in[0];
  const float* wq      = (const float*)d_in[1];
  const float* wk      = (const float*)d_in[2];
  const float* wv      = (const float*)d_in[3];
  const float* wo      = (const float*)d_in[4];
  const float* beta    = (const float*)d_in[5];
  const float* memory  = (const float*)d_in[6];
  const float* memnorm = (const float*)d_in[7];
  float* out = (float*)d_out;

  char* ws = (char*)d_ws;
  __bf16* hsb  = (__bf16*)(ws);                        // 8 MB  [4096][1024]
  __bf16* wqb  = (__bf16*)(ws + ((size_t)8  << 20));   // 2 MB
  __bf16* wkb  = (__bf16*)(ws + ((size_t)10 << 20));   // 2 MB
  __bf16* wvb  = (__bf16*)(ws + ((size_t)12 << 20));   // 2 MB
  __bf16* wob  = (__bf16*)(ws + ((size_t)14 << 20));   // 2 MB
  __bf16* qbuf = (__bf16*)(ws + ((size_t)16 << 20));   // 8 MB  [32][2048][64]
  __bf16* kbuf = (__bf16*)(ws + ((size_t)24 << 20));   // 8 MB
  __bf16* vtb  = (__bf16*)(ws + ((size_t)32 << 20));   // 8 MB  [32][64][2048]
  __bf16* comb = (__bf16*)(ws + ((size_t)40 << 20));   // 8 MB  [4096][1024]

  cvt_all<<<8192, 256, 0, stream>>>(hs, wq, wk, wv, wo, hsb, wqb, wkb, wvb, wob);

  qkv_gemm<<<768, 256, 0, stream>>>(hsb, wqb, wkb, wvb, qbuf, kbuf, vtb);

  attn_kernel<<<1024, 256, 0, stream>>>(qbuf, kbuf, vtb, memory, memnorm, beta, comb);

  gemm_out<<<dim3(32, 16), 256, 0, stream>>>(comb, wob, out, 4096, 1024);
}